// Round 8
// baseline (269.007 us; speedup 1.0000x reference)
//
#include <hip/hip_runtime.h>
#include <math.h>

constexpr int B = 2, S = 2048, E = 1024, H = 16, D = 64;
constexpr int M = B * S;  // 4096

typedef __attribute__((ext_vector_type(8))) short short8;
typedef __attribute__((ext_vector_type(8))) _Float16 half8;
typedef __attribute__((ext_vector_type(4))) float f32x4;
#define MFMA_BF16 __builtin_amdgcn_mfma_f32_16x16x32_bf16
#define MFMA_F16 __builtin_amdgcn_mfma_f32_16x16x32_f16
// wait until at most N vector-memory ops outstanding; leave lgkm/exp unconstrained
#define WAITCNT_VM(N) __builtin_amdgcn_s_waitcnt(0xF70 | (N))

// Split fp32 into hi = bf16-truncate(x), lo = bf16-truncate(x - hi). Combined rel err ~2^-16.
__device__ __forceinline__ void split1(float f, short* h, short* l) {
  unsigned u = __float_as_uint(f);
  *h = (short)(u >> 16);
  float r = f - __uint_as_float(u & 0xFFFF0000u);
  *l = (short)(__float_as_uint(r) >> 16);
}
__device__ __forceinline__ short f2h(float f) {
  _Float16 h = (_Float16)f;
  short s;
  __builtin_memcpy(&s, &h, 2);
  return s;
}
__device__ __forceinline__ float h2f(short s) {
  _Float16 h;
  __builtin_memcpy(&h, &s, 2);
  return (float)h;
}

// Async global->LDS DMA, 16B per lane. LDS dest = wave-uniform base + lane*16.
__device__ __forceinline__ void gload16(const void* g, const void* l) {
  __builtin_amdgcn_global_load_lds(
      (const __attribute__((address_space(1))) unsigned*)g,
      (__attribute__((address_space(3))) unsigned*)l, 16, 0, 0);
}

struct SArgs {  // split-bf16 path
  const short* Ah; const short* Al;  // A [Mrows x K] bf16 hi/lo
  const short* Bh; const short* Bl;  // B [N x K] bf16 hi/lo
  const float* bias;                 // WEMIT=0
  float* C;                          // WEMIT=0: fp32 out
  short* Ch; short* Cl;              // WEMIT=1: split bf16 out
};
struct HArgs {  // fp16 path
  const short* A; const short* Bm;   // fp16 bits
  const float* bias;                 // WEMIT=0
  short* C;                          // fp16 out
  float* Zrow;                       // if set (WEMIT=0): store exp(val), += rowsum exp
};

// One dispatch, two precision modes (wave-uniform branch on blockIdx.z):
//   z==0: split-bf16 3-MFMA, single-buffered LDS (q path, ~2^-22 rel err)
//   z>=1: fp16 1-MFMA, double-buffered pipelined LDS (k/v paths)
// BM in {64,128}, BN=128, 256 threads = 4 waves (2x2), K%64==0.
template <int BM, int WEMIT>
__global__ __launch_bounds__(256, 2) void gemm_combo(SArgs s, HArgs ha, HArgs hb, int K, int N) {
  __shared__ short lds[(BM / 8 + 16) * 512];
  const int tid = threadIdx.x, wave = tid >> 6, lane = tid & 63;
  const int bm = blockIdx.x * BM, bn = blockIdx.y * 128;
  const int fr = lane & 15, fq = lane >> 4;
  const int wm = (wave & 1) * (BM / 2), wn = (wave >> 1) * 64;
  constexpr int MT = BM / 32;

  if (blockIdx.z == 0) {
    // ---------------- split-bf16 3-MFMA path ----------------
    constexpr int SA = BM / 16;
    constexpr int TOT = 2 * SA + 16;
    constexpr int PW = TOT / 4;
    const short* gb[PW];
#pragma unroll
    for (int j = 0; j < PW; ++j) {
      const int n = wave * PW + j;
      const short* src; int seg, rowbase;
      if (n < SA)              { src = s.Ah; seg = n;            rowbase = bm; }
      else if (n < 2 * SA)     { src = s.Al; seg = n - SA;       rowbase = bm; }
      else if (n < 2 * SA + 8) { src = s.Bh; seg = n - 2 * SA;   rowbase = bn; }
      else                     { src = s.Bl; seg = n - 2 * SA - 8; rowbase = bn; }
      const int r = seg * 16 + (lane >> 2);   // row within tile
      const int p = lane & 3;                 // LDS chunk slot this lane fills
      const int q = (p - ((r >> 1) & 3)) & 3; // k-chunk that belongs in slot p (swizzle)
      gb[j] = src + (size_t)(rowbase + r) * K + q * 8;
    }
    int aoh[MT], aol[MT], boh[4], bol[4];
#pragma unroll
    for (int mi = 0; mi < MT; ++mi) {
      const int r = wm + mi * 16 + fr;
      const int slot = (fq + ((r >> 1) & 3)) & 3;
      aoh[mi] = r * 32 + slot * 8;
      aol[mi] = BM * 32 + aoh[mi];
    }
#pragma unroll
    for (int ni = 0; ni < 4; ++ni) {
      const int r = wn + ni * 16 + fr;
      const int slot = (fq + ((r >> 1) & 3)) & 3;
      boh[ni] = 2 * BM * 32 + r * 32 + slot * 8;
      bol[ni] = boh[ni] + 4096;
    }
    f32x4 acc[MT][4] = {};
    const int ldsW = wave * PW * 512;
    for (int k0 = 0; k0 < K; k0 += 32) {
#pragma unroll
      for (int j = 0; j < PW; ++j) gload16(gb[j] + k0, &lds[ldsW + j * 512]);
      __syncthreads();  // compiler drains vmcnt(0) before s_barrier
      short8 ah[MT], al[MT], bh4[4], bl4[4];
#pragma unroll
      for (int mi = 0; mi < MT; ++mi) {
        ah[mi] = *(const short8*)&lds[aoh[mi]];
        al[mi] = *(const short8*)&lds[aol[mi]];
      }
#pragma unroll
      for (int ni = 0; ni < 4; ++ni) {
        bh4[ni] = *(const short8*)&lds[boh[ni]];
        bl4[ni] = *(const short8*)&lds[bol[ni]];
      }
#pragma unroll
      for (int mi = 0; mi < MT; ++mi)
#pragma unroll
        for (int ni = 0; ni < 4; ++ni) {
          acc[mi][ni] = MFMA_BF16(ah[mi], bh4[ni], acc[mi][ni], 0, 0, 0);
          acc[mi][ni] = MFMA_BF16(ah[mi], bl4[ni], acc[mi][ni], 0, 0, 0);
          acc[mi][ni] = MFMA_BF16(al[mi], bh4[ni], acc[mi][ni], 0, 0, 0);
        }
      __syncthreads();
    }
    // epilogue: C/D layout col=lane&15, row=(lane>>4)*4+reg (m89-verified)
    if (WEMIT == 0) {
      float* C = s.C;
#pragma unroll
      for (int ni = 0; ni < 4; ++ni) {
        const int n = bn + wn + ni * 16 + fr;
        const float bv = s.bias[n];
#pragma unroll
        for (int mi = 0; mi < MT; ++mi) {
          const int m0 = bm + wm + mi * 16 + fq * 4;
#pragma unroll
          for (int r2 = 0; r2 < 4; ++r2)
            C[(size_t)(m0 + r2) * N + n] = acc[mi][ni][r2] + bv;
        }
      }
    } else {
      short* Chp = s.Ch; short* Clp = s.Cl;
#pragma unroll
      for (int ni = 0; ni < 4; ++ni) {
        const int n = bn + wn + ni * 16 + fr;
#pragma unroll
        for (int mi = 0; mi < MT; ++mi) {
          const int m0 = bm + wm + mi * 16 + fq * 4;
#pragma unroll
          for (int r2 = 0; r2 < 4; ++r2) {
            short hh, ll;
            split1(acc[mi][ni][r2], &hh, &ll);
            Chp[(size_t)(m0 + r2) * N + n] = hh;
            Clp[(size_t)(m0 + r2) * N + n] = ll;
          }
        }
      }
    }
    return;
  }

  // ---------------- fp16 1-MFMA path (pipelined) ----------------
  const HArgs h = (blockIdx.z == 1) ? ha : hb;
  constexpr int SAh = BM / 16;
  constexpr int TOTh = SAh + 8;
  constexpr int PWh = TOTh / 4;
  const short* gb[PWh];
#pragma unroll
  for (int j = 0; j < PWh; ++j) {
    const int n = wave * PWh + j;
    const short* src; int seg, rowbase;
    if (n < SAh) { src = h.A;  seg = n;       rowbase = bm; }
    else         { src = h.Bm; seg = n - SAh; rowbase = bn; }
    const int r = seg * 16 + (lane >> 2);
    const int p = lane & 3;
    const int q = (p - ((r >> 1) & 3)) & 3;
    gb[j] = src + (size_t)(rowbase + r) * K + q * 8;
  }
  int ao[MT], bo[4];
#pragma unroll
  for (int mi = 0; mi < MT; ++mi) {
    const int r = wm + mi * 16 + fr;
    ao[mi] = r * 32 + (((fq + ((r >> 1) & 3)) & 3)) * 8;
  }
#pragma unroll
  for (int ni = 0; ni < 4; ++ni) {
    const int r = wn + ni * 16 + fr;
    bo[ni] = BM * 32 + r * 32 + (((fq + ((r >> 1) & 3)) & 3)) * 8;
  }
  f32x4 acc[MT][4] = {};
  const int ldsW = wave * PWh * 512;
  auto stageAll = [&](int buf, int k0) {
#pragma unroll
    for (int j = 0; j < PWh; ++j)
      gload16(gb[j] + k0, &lds[buf * TOTh * 512 + ldsW + j * 512]);
  };
  stageAll(0, 0);
  stageAll(1, 32);
  int buf = 0;
  for (int k0 = 0; k0 < K; k0 += 32) {
    if (k0 + 32 < K) WAITCNT_VM(PWh); else WAITCNT_VM(0);
    __builtin_amdgcn_s_barrier();
    half8 ah[MT], bh4[4];
    const int bb = buf * TOTh * 512;
#pragma unroll
    for (int mi = 0; mi < MT; ++mi) ah[mi] = *(const half8*)&lds[bb + ao[mi]];
#pragma unroll
    for (int ni = 0; ni < 4; ++ni) bh4[ni] = *(const half8*)&lds[bb + bo[ni]];
#pragma unroll
    for (int mi = 0; mi < MT; ++mi)
#pragma unroll
      for (int ni = 0; ni < 4; ++ni)
        acc[mi][ni] = MFMA_F16(ah[mi], bh4[ni], acc[mi][ni], 0, 0, 0);
    __builtin_amdgcn_s_barrier();  // all waves done reading lds[buf]
    if (k0 + 64 < K) stageAll(buf, k0 + 64);
    buf ^= 1;
  }
  if (WEMIT == 0) {
    short* C = h.C;
    float bv4[4];
#pragma unroll
    for (int ni = 0; ni < 4; ++ni) bv4[ni] = h.bias[bn + wn + ni * 16 + fr];
#pragma unroll
    for (int mi = 0; mi < MT; ++mi)
#pragma unroll
      for (int r2 = 0; r2 < 4; ++r2) {
        const int m = bm + wm + mi * 16 + fq * 4 + r2;
        float vals[4];
#pragma unroll
        for (int ni = 0; ni < 4; ++ni) vals[ni] = acc[mi][ni][r2] + bv4[ni];
        if (h.Zrow) {  // k path: store exp(logit), accumulate row sums of exp
          float es = 0.f;
#pragma unroll
          for (int ni = 0; ni < 4; ++ni) { vals[ni] = __expf(vals[ni]); es += vals[ni]; }
#pragma unroll
          for (int off = 1; off < 16; off <<= 1) es += __shfl_xor(es, off, 16);
          if (fr == 0) atomicAdd(&h.Zrow[m], es);
        }
#pragma unroll
        for (int ni = 0; ni < 4; ++ni)
          C[(size_t)m * N + bn + wn + ni * 16 + fr] = f2h(vals[ni]);
      }
  } else {
    short* C = h.C;
#pragma unroll
    for (int ni = 0; ni < 4; ++ni) {
      const int n = bn + wn + ni * 16 + fr;
#pragma unroll
      for (int mi = 0; mi < MT; ++mi) {
        const int m0 = bm + wm + mi * 16 + fq * 4;
#pragma unroll
        for (int r2 = 0; r2 < 4; ++r2)
          C[(size_t)(m0 + r2) * N + n] = f2h(acc[mi][ni][r2]);
      }
    }
  }
}

// One fused prep dispatch (4352 blocks): conversions + transposes + bias combines.
__global__ __launch_bounds__(256) void prep(
    const float* __restrict__ hs, short* hs_h, short* hs_l, short* hs_f,
    const float* __restrict__ Wfq, short* Wfq_h, short* Wfq_l,
    const float* __restrict__ Wfk, short* Wfk_f,
    const float* __restrict__ Wv, short* Wv_f,
    const float* __restrict__ Wq, short* WqT_h, short* WqT_l,
    const float* __restrict__ Wk, short* WkT_f,
    const float* __restrict__ bq, const float* __restrict__ bfq, float* bcQ,
    const float* __restrict__ bk, const float* __restrict__ bfk, float* bcK) {
  __shared__ float tb[32][33];
  const int blk = blockIdx.x, tid = threadIdx.x;
  if (blk < 1024) {
#pragma unroll
    for (int p = 0; p < 4; ++p) {
      const int i = blk * 1024 + p * 256 + tid;
      float4 v = ((const float4*)hs)[i];
      short4 hh, ll;
      split1(v.x, &hh.x, &ll.x); split1(v.y, &hh.y, &ll.y);
      split1(v.z, &hh.z, &ll.z); split1(v.w, &hh.w, &ll.w);
      ((short4*)hs_h)[i] = hh; ((short4*)hs_l)[i] = ll;
      ((short4*)hs_f)[i] = make_short4(f2h(v.x), f2h(v.y), f2h(v.z), f2h(v.w));
    }
  } else if (blk < 1280) {
    const int base = blk - 1024;
#pragma unroll
    for (int p = 0; p < 4; ++p) {
      const int i = base * 1024 + p * 256 + tid;
      float4 v = ((const float4*)Wfq)[i];
      short4 hh, ll;
      split1(v.x, &hh.x, &ll.x); split1(v.y, &hh.y, &ll.y);
      split1(v.z, &hh.z, &ll.z); split1(v.w, &hh.w, &ll.w);
      ((short4*)Wfq_h)[i] = hh; ((short4*)Wfq_l)[i] = ll;
    }
  } else if (blk < 1792) {
    const int base = blk - 1280;  // [0,512): first 256 = Wfk, next 256 = Wv
    const float* src = (base < 256) ? Wfk : Wv;
    short* dst = (base < 256) ? Wfk_f : Wv_f;
    const int bb = base & 255;
#pragma unroll
    for (int p = 0; p < 4; ++p) {
      const int i = bb * 1024 + p * 256 + tid;
      float4 v = ((const float4*)src)[i];
      ((short4*)dst)[i] = make_short4(f2h(v.x), f2h(v.y), f2h(v.z), f2h(v.w));
    }
  } else if (blk < 2816) {
    const int tt = blk - 1792;
    const int bx = (tt & 31) * 32, by = (tt >> 5) * 32;
    const int x = tid & 31, y0 = tid >> 5;
#pragma unroll
    for (int i = 0; i < 32; i += 8) tb[y0 + i][x] = Wq[(size_t)(by + y0 + i) * E + bx + x];
    __syncthreads();
#pragma unroll
    for (int i = 0; i < 32; i += 8) {
      short hh, ll;
      split1(tb[x][y0 + i], &hh, &ll);
      const size_t o = (size_t)(bx + y0 + i) * E + by + x;
      WqT_h[o] = hh; WqT_l[o] = ll;
    }
  } else if (blk < 3840) {
    const int tt = blk - 2816;
    const int bx = (tt & 31) * 32, by = (tt >> 5) * 32;
    const int x = tid & 31, y0 = tid >> 5;
#pragma unroll
    for (int i = 0; i < 32; i += 8) tb[y0 + i][x] = Wk[(size_t)(by + y0 + i) * E + bx + x];
    __syncthreads();
#pragma unroll
    for (int i = 0; i < 32; i += 8)
      WkT_f[(size_t)(bx + y0 + i) * E + by + x] = f2h(tb[x][y0 + i]);
  } else {
    const int t = blk - 3840;
    const float* Wf = (t < 256) ? Wfq : Wfk;
    const float* bin = (t < 256) ? bq : bk;
    const float* bf = (t < 256) ? bfq : bfk;
    float* o = (t < 256) ? bcQ : bcK;
    const int n = (t & 255) * 4 + (tid >> 6);
    const int lane = tid & 63;
    float sacc = 0.f;
    for (int j = lane; j < E; j += 64) sacc += Wf[(size_t)n * E + j] * bin[j];
#pragma unroll
    for (int off = 32; off; off >>= 1) sacc += __shfl_xor(sacc, off, 64);
    if (lane == 0) o[n] = sacc + bf[n];
  }
}

// KV[bh] += sum_t (e_t/Z_t) v_t^T ; ksum[bh] += sum_t e_t/Z_t.  Atomic into zeroed ws.
// Grid (32 bh, 32 chunks of 64 t). Vectorized short4 loads. 1024 blocks.
__global__ __launch_bounds__(256) void kv_part(const short* __restrict__ kh,
                                               const short* __restrict__ vh,
                                               const float* __restrict__ Zk,
                                               float* __restrict__ KV,
                                               float* __restrict__ ksum) {
  const int bh = blockIdx.x;
  const int b = bh / H, h = bh % H;
  const int t0 = blockIdx.y * 64;
  const short* kbase = kh + (size_t)b * S * E + (size_t)h * D;
  const short* vbase = vh + (size_t)b * S * E + (size_t)h * D;
  __shared__ float ks[16][D];
  __shared__ float vs[16][D];
  __shared__ float invZs[64];
  const int tid = threadIdx.x;
  if (tid < 64) invZs[tid] = 1.0f / Zk[b * S + t0 + tid];  // batch offset b*S!
  const int a4 = tid & 15, b4 = tid >> 4;
  const int lt = tid >> 4, d4 = (tid & 15) * 4;  // staging: row-in-tile, d offset
  float acc[4][4] = {};
  float ksm[4] = {};
  for (int ts = 0; ts < 64; ts += 16) {
    __syncthreads();
    const size_t roff = (size_t)(t0 + ts + lt) * E + d4;
    short4 k4 = *(const short4*)(kbase + roff);
    short4 v4 = *(const short4*)(vbase + roff);
    const float iz = invZs[ts + lt];
    ks[lt][d4 + 0] = h2f(k4.x) * iz; ks[lt][d4 + 1] = h2f(k4.y) * iz;
    ks[lt][d4 + 2] = h2f(k4.z) * iz; ks[lt][d4 + 3] = h2f(k4.w) * iz;
    vs[lt][d4 + 0] = h2f(v4.x); vs[lt][d4 + 1] = h2f(v4.y);
    vs[lt][d4 + 2] = h2f(v4.z); vs[lt][d4 + 3] = h2f(v4.w);
    __syncthreads();
#pragma unroll
    for (int tt = 0; tt < 16; ++tt) {
      float kk4[4], vv4[4];
#pragma unroll
      for (int i = 0; i < 4; ++i) kk4[i] = ks[tt][a4 * 4 + i];
#pragma unroll
      for (int j = 0; j < 4; ++j) vv4[j] = vs[tt][b4 * 4 + j];
#pragma unroll
      for (int i = 0; i < 4; ++i) {
        ksm[i] += kk4[i];
#pragma unroll
        for (int j = 0; j < 4; ++j) acc[i][j] = fmaf(kk4[i], vv4[j], acc[i][j]);
      }
    }
  }
  float* kvb = KV + (size_t)bh * 4096;
#pragma unroll
  for (int i = 0; i < 4; ++i)
#pragma unroll
    for (int j = 0; j < 4; ++j)
      atomicAdd(&kvb[(a4 * 4 + i) * 64 + b4 * 4 + j], acc[i][j]);
  if (b4 == 0) {
#pragma unroll
    for (int i = 0; i < 4; ++i) atomicAdd(&ksum[bh * 64 + a4 * 4 + i], ksm[i]);
  }
}

// Output: grid (32 bh, 64 chunks of 32 rows) = 2048 blocks. KV[bh] staged in LDS.
// Each wave: 4 rows concurrently (lane = r2*16+g; d' = g*4..+3 float4), 8 rows total.
__global__ __launch_bounds__(256) void out_v5(const float* __restrict__ qf,
                                              const float* __restrict__ KV,
                                              const float* __restrict__ ksum,
                                              float* __restrict__ out) {
  const int bh = blockIdx.x;
  const int b = bh >> 4, h = bh & 15;
  __shared__ float KVs[64][64];  // LD=64: float4 reads are 2-way bank-aliased (free)
  __shared__ float kss[64];
  __shared__ float qs[4][4][64];
  const int tid = threadIdx.x, wave = tid >> 6, lane = tid & 63;
  const int r2 = lane >> 4, g = lane & 15;
  for (int i = tid; i < 1024; i += 256)
    ((float4*)KVs)[i] = ((const float4*)(KV + (size_t)bh * 4096))[i];
  if (tid < 64) kss[tid] = ksum[bh * 64 + tid];
  __syncthreads();
  const float4 ks4 = *(const float4*)&kss[g * 4];
  const int row0 = blockIdx.y * 32 + wave * 8;
#pragma unroll
  for (int it = 0; it < 2; ++it) {
    const int row = row0 + it * 4 + r2;
    const size_t rowoff = ((size_t)b * S + row) * E + h * 64;
    float4 u = *(const float4*)(qf + rowoff + g * 4);
    u.x = __expf(u.x); u.y = __expf(u.y); u.z = __expf(u.z); u.w = __expf(u.w);
    float dn = u.x * ks4.x + u.y * ks4.y + u.z * ks4.z + u.w * ks4.w;
#pragma unroll
    for (int off = 1; off < 16; off <<= 1) dn += __shfl_xor(dn, off, 16);
    *(float4*)&qs[wave][r2][g * 4] = u;
    __syncthreads();  // publish qs (uniform: all waves run 2 iters)
    float nx = 0.f, ny = 0.f, nz = 0.f, nw = 0.f;
#pragma unroll
    for (int d = 0; d < 64; ++d) {
      const float qd = qs[wave][r2][d];
      const float4 kv = *(const float4*)&KVs[d][g * 4];
      nx = fmaf(qd, kv.x, nx); ny = fmaf(qd, kv.y, ny);
      nz = fmaf(qd, kv.z, nz); nw = fmaf(qd, kv.w, nw);
    }
    const float inv = 1.0f / dn;
    float4 o4 = make_float4(nx * inv, ny * inv, nz * inv, nw * inv);
    *(float4*)(out + rowoff + g * 4) = o4;
    __syncthreads();  // qs reused next iteration
  }
}

extern "C" void kernel_launch(void* const* d_in, const int* in_sizes, int n_in,
                              void* d_out, int out_size, void* d_ws, size_t ws_size,
                              hipStream_t stream) {
  const float* hs = (const float*)d_in[0];
  const float* Wq = (const float*)d_in[1];
  const float* bq = (const float*)d_in[2];
  const float* Wk = (const float*)d_in[3];
  const float* bk = (const float*)d_in[4];
  const float* Wv = (const float*)d_in[5];
  const float* bv = (const float*)d_in[6];
  const float* Wfq = (const float*)d_in[7];
  const float* bfq = (const float*)d_in[8];
  const float* Wfk = (const float*)d_in[9];
  const float* bfk = (const float*)d_in[10];
  float* out = (float*)d_out;

  const size_t MEG = 1024 * 1024;
  float* ws = (float*)d_ws;
  float* qf = ws;                                       // [M,E] fp32 q logits (16 MB)
  short* kh = (short*)(ws + 4 * MEG);                   // [M,E] fp16 e=exp(k logit) (8 MB)
  short* vh = (short*)(ws + 6 * MEG);                   // [M,E] fp16 v (8 MB)
  short* hs_h = (short*)(ws + 8 * MEG);                 // bf16 hi (8 MB)
  short* hs_l = (short*)(ws + 10 * MEG);                // bf16 lo (8 MB)
  short* hs_f = (short*)(ws + 12 * MEG);                // fp16 (8 MB)
  short* Wfq_h = (short*)(ws + 14 * MEG);
  short* Wfq_l = (short*)(ws + 14 * MEG + 512 * 1024);
  short* WqT_h = (short*)(ws + 15 * MEG);
  short* WqT_l = (short*)(ws + 15 * MEG + 512 * 1024);
  short* Wfk_f = (short*)(ws + 16 * MEG);
  short* WkT_f = (short*)(ws + 16 * MEG + 512 * 1024);
  short* Wv_f = (short*)(ws + 17 * MEG);
  short* WcQ_h = (short*)(ws + 17 * MEG + 512 * 1024);
  short* WcQ_l = (short*)(ws + 18 * MEG);
  short* WcK_f = (short*)(ws + 18 * MEG + 512 * 1024);
  float* bcQ = ws + 19 * MEG;
  float* bcK = bcQ + 1024;
  float* Zk = bcK + 1024;                               // [M]
  float* KV = Zk + M;                                   // [32][64][64]
  float* ksum = KV + 32 * 4096;                         // [32][64]

  // 0) Zero Zk + KV + ksum (contiguous, ~0.55 MB).
  hipMemsetAsync(Zk, 0, (size_t)(M + 32 * 4096 + 32 * 64) * sizeof(float), stream);
  // 1) Fused prep: conversions + transposes + bias combines.
  prep<<<4352, 256, 0, stream>>>(hs, hs_h, hs_l, hs_f,
                                 Wfq, Wfq_h, Wfq_l, Wfk, Wfk_f, Wv, Wv_f,
                                 Wq, WqT_h, WqT_l, Wk, WkT_f,
                                 bq, bfq, bcQ, bk, bfk, bcK);
  // 2) Combined weights: z=0 split WcQ = Wfq@Wq, z=1 fp16 WcK = Wfk@Wk.
  SArgs sw = {Wfq_h, Wfq_l, WqT_h, WqT_l, nullptr, nullptr, WcQ_h, WcQ_l};
  HArgs hw = {Wfk_f, WkT_f, nullptr, WcK_f, nullptr};
  gemm_combo<64, 1><<<dim3(16, 8, 2), 256, 0, stream>>>(sw, hw, hw, E, E);
  // 3) Big GEMM: z=0 split q logits (fp32); z=1 fp16 k -> exp stored fp16 + Zk; z=2 fp16 v.
  SArgs sb = {hs_h, hs_l, WcQ_h, WcQ_l, bcQ, qf, nullptr, nullptr};
  HArgs hk = {hs_f, WcK_f, bcK, kh, Zk};
  HArgs hv = {hs_f, Wv_f, bv, vh, nullptr};
  gemm_combo<128, 0><<<dim3(32, 8, 3), 256, 0, stream>>>(sb, hk, hv, E, E);
  // 4) KV + ksum accumulation (atomics, 1024 blocks).
  kv_part<<<dim3(B * H, S / 64), 256, 0, stream>>>(kh, vh, Zk, KV, ksum);
  // 5) Output (2048 blocks; exp applied inline; q normalization cancels).
  out_v5<<<dim3(B * H, S / 32), 256, 0, stream>>>(qf, KV, ksum, out);
}

// Round 9
// 221.065 us; speedup vs baseline: 1.2169x; 1.2169x over previous
//
#include <hip/hip_runtime.h>
#include <math.h>

constexpr int B = 2, S = 2048, E = 1024, H = 16, D = 64;
constexpr int M = B * S;  // 4096
constexpr int CH = 16;    // kv chunks per (b,h), 128 t each

typedef __attribute__((ext_vector_type(8))) short short8;
typedef __attribute__((ext_vector_type(8))) _Float16 half8;
typedef __attribute__((ext_vector_type(4))) float f32x4;
#define MFMA_BF16 __builtin_amdgcn_mfma_f32_16x16x32_bf16
#define MFMA_F16 __builtin_amdgcn_mfma_f32_16x16x32_f16
// wait until at most N vector-memory ops outstanding; leave lgkm/exp unconstrained
#define WAITCNT_VM(N) __builtin_amdgcn_s_waitcnt(0xF70 | (N))

// Split fp32 into hi = bf16-truncate(x), lo = bf16-truncate(x - hi). Combined rel err ~2^-16.
__device__ __forceinline__ void split1(float f, short* h, short* l) {
  unsigned u = __float_as_uint(f);
  *h = (short)(u >> 16);
  float r = f - __uint_as_float(u & 0xFFFF0000u);
  *l = (short)(__float_as_uint(r) >> 16);
}
__device__ __forceinline__ short f2h(float f) {
  _Float16 h = (_Float16)f;
  short s;
  __builtin_memcpy(&s, &h, 2);
  return s;
}
__device__ __forceinline__ float h2f(short s) {
  _Float16 h;
  __builtin_memcpy(&h, &s, 2);
  return (float)h;
}

// Async global->LDS DMA, 16B per lane. LDS dest = wave-uniform base + lane*16.
__device__ __forceinline__ void gload16(const void* g, const void* l) {
  __builtin_amdgcn_global_load_lds(
      (const __attribute__((address_space(1))) unsigned*)g,
      (__attribute__((address_space(3))) unsigned*)l, 16, 0, 0);
}

struct SArgs {  // split-bf16 path
  const short* Ah; const short* Al;  // A [Mrows x K] bf16 hi/lo
  const short* Bh; const short* Bl;  // B [N x K] bf16 hi/lo
  const float* bias;                 // WEMIT=0
  float* C;                          // WEMIT=0: fp32 out
  short* Ch; short* Cl;              // WEMIT=1: split bf16 out
};
struct HArgs {  // fp16 path
  const short* A; const short* Bm;   // fp16 bits
  const float* bias;                 // WEMIT=0
  short* C;                          // fp16 out
  float* Zrow;                       // if set (WEMIT=0): store exp(val), += rowsum exp
};

// One dispatch, two precision modes (wave-uniform branch on blockIdx.z):
//   z==0: split-bf16 3-MFMA, single-buffered LDS (q path, ~2^-22 rel err)
//   z>=1: fp16 1-MFMA, double-buffered pipelined LDS (k/v paths)
// BM in {64,128}, BN=128, 256 threads = 4 waves (2x2), K%64==0.
template <int BM, int WEMIT>
__global__ __launch_bounds__(256, 2) void gemm_combo(SArgs s, HArgs ha, HArgs hb, int K, int N) {
  __shared__ short lds[(BM / 8 + 16) * 512];
  const int tid = threadIdx.x, wave = tid >> 6, lane = tid & 63;
  const int bm = blockIdx.x * BM, bn = blockIdx.y * 128;
  const int fr = lane & 15, fq = lane >> 4;
  const int wm = (wave & 1) * (BM / 2), wn = (wave >> 1) * 64;
  constexpr int MT = BM / 32;

  if (blockIdx.z == 0) {
    // ---------------- split-bf16 3-MFMA path ----------------
    constexpr int SA = BM / 16;
    constexpr int TOT = 2 * SA + 16;
    constexpr int PW = TOT / 4;
    const short* gb[PW];
#pragma unroll
    for (int j = 0; j < PW; ++j) {
      const int n = wave * PW + j;
      const short* src; int seg, rowbase;
      if (n < SA)              { src = s.Ah; seg = n;            rowbase = bm; }
      else if (n < 2 * SA)     { src = s.Al; seg = n - SA;       rowbase = bm; }
      else if (n < 2 * SA + 8) { src = s.Bh; seg = n - 2 * SA;   rowbase = bn; }
      else                     { src = s.Bl; seg = n - 2 * SA - 8; rowbase = bn; }
      const int r = seg * 16 + (lane >> 2);   // row within tile
      const int p = lane & 3;                 // LDS chunk slot this lane fills
      const int q = (p - ((r >> 1) & 3)) & 3; // k-chunk that belongs in slot p (swizzle)
      gb[j] = src + (size_t)(rowbase + r) * K + q * 8;
    }
    int aoh[MT], aol[MT], boh[4], bol[4];
#pragma unroll
    for (int mi = 0; mi < MT; ++mi) {
      const int r = wm + mi * 16 + fr;
      const int slot = (fq + ((r >> 1) & 3)) & 3;
      aoh[mi] = r * 32 + slot * 8;
      aol[mi] = BM * 32 + aoh[mi];
    }
#pragma unroll
    for (int ni = 0; ni < 4; ++ni) {
      const int r = wn + ni * 16 + fr;
      const int slot = (fq + ((r >> 1) & 3)) & 3;
      boh[ni] = 2 * BM * 32 + r * 32 + slot * 8;
      bol[ni] = boh[ni] + 4096;
    }
    f32x4 acc[MT][4] = {};
    const int ldsW = wave * PW * 512;
    for (int k0 = 0; k0 < K; k0 += 32) {
#pragma unroll
      for (int j = 0; j < PW; ++j) gload16(gb[j] + k0, &lds[ldsW + j * 512]);
      __syncthreads();  // compiler drains vmcnt(0) before s_barrier
      short8 ah[MT], al[MT], bh4[4], bl4[4];
#pragma unroll
      for (int mi = 0; mi < MT; ++mi) {
        ah[mi] = *(const short8*)&lds[aoh[mi]];
        al[mi] = *(const short8*)&lds[aol[mi]];
      }
#pragma unroll
      for (int ni = 0; ni < 4; ++ni) {
        bh4[ni] = *(const short8*)&lds[boh[ni]];
        bl4[ni] = *(const short8*)&lds[bol[ni]];
      }
#pragma unroll
      for (int mi = 0; mi < MT; ++mi)
#pragma unroll
        for (int ni = 0; ni < 4; ++ni) {
          acc[mi][ni] = MFMA_BF16(ah[mi], bh4[ni], acc[mi][ni], 0, 0, 0);
          acc[mi][ni] = MFMA_BF16(ah[mi], bl4[ni], acc[mi][ni], 0, 0, 0);
          acc[mi][ni] = MFMA_BF16(al[mi], bh4[ni], acc[mi][ni], 0, 0, 0);
        }
      __syncthreads();
    }
    // epilogue: C/D layout col=lane&15, row=(lane>>4)*4+reg (m89-verified)
    if (WEMIT == 0) {
      float* C = s.C;
#pragma unroll
      for (int ni = 0; ni < 4; ++ni) {
        const int n = bn + wn + ni * 16 + fr;
        const float bv = s.bias[n];
#pragma unroll
        for (int mi = 0; mi < MT; ++mi) {
          const int m0 = bm + wm + mi * 16 + fq * 4;
#pragma unroll
          for (int r2 = 0; r2 < 4; ++r2)
            C[(size_t)(m0 + r2) * N + n] = acc[mi][ni][r2] + bv;
        }
      }
    } else {
      short* Chp = s.Ch; short* Clp = s.Cl;
#pragma unroll
      for (int ni = 0; ni < 4; ++ni) {
        const int n = bn + wn + ni * 16 + fr;
#pragma unroll
        for (int mi = 0; mi < MT; ++mi) {
          const int m0 = bm + wm + mi * 16 + fq * 4;
#pragma unroll
          for (int r2 = 0; r2 < 4; ++r2) {
            short hh, ll;
            split1(acc[mi][ni][r2], &hh, &ll);
            Chp[(size_t)(m0 + r2) * N + n] = hh;
            Clp[(size_t)(m0 + r2) * N + n] = ll;
          }
        }
      }
    }
    return;
  }

  // ---------------- fp16 1-MFMA path (pipelined) ----------------
  const HArgs h = (blockIdx.z == 1) ? ha : hb;
  constexpr int SAh = BM / 16;
  constexpr int TOTh = SAh + 8;
  constexpr int PWh = TOTh / 4;
  const short* gb[PWh];
#pragma unroll
  for (int j = 0; j < PWh; ++j) {
    const int n = wave * PWh + j;
    const short* src; int seg, rowbase;
    if (n < SAh) { src = h.A;  seg = n;       rowbase = bm; }
    else         { src = h.Bm; seg = n - SAh; rowbase = bn; }
    const int r = seg * 16 + (lane >> 2);
    const int p = lane & 3;
    const int q = (p - ((r >> 1) & 3)) & 3;
    gb[j] = src + (size_t)(rowbase + r) * K + q * 8;
  }
  int ao[MT], bo[4];
#pragma unroll
  for (int mi = 0; mi < MT; ++mi) {
    const int r = wm + mi * 16 + fr;
    ao[mi] = r * 32 + (((fq + ((r >> 1) & 3)) & 3)) * 8;
  }
#pragma unroll
  for (int ni = 0; ni < 4; ++ni) {
    const int r = wn + ni * 16 + fr;
    bo[ni] = BM * 32 + r * 32 + (((fq + ((r >> 1) & 3)) & 3)) * 8;
  }
  f32x4 acc[MT][4] = {};
  const int ldsW = wave * PWh * 512;
  auto stageAll = [&](int buf, int k0) {
#pragma unroll
    for (int j = 0; j < PWh; ++j)
      gload16(gb[j] + k0, &lds[buf * TOTh * 512 + ldsW + j * 512]);
  };
  stageAll(0, 0);
  stageAll(1, 32);
  int buf = 0;
  for (int k0 = 0; k0 < K; k0 += 32) {
    if (k0 + 32 < K) WAITCNT_VM(PWh); else WAITCNT_VM(0);
    __builtin_amdgcn_s_barrier();
    half8 ah[MT], bh4[4];
    const int bb = buf * TOTh * 512;
#pragma unroll
    for (int mi = 0; mi < MT; ++mi) ah[mi] = *(const half8*)&lds[bb + ao[mi]];
#pragma unroll
    for (int ni = 0; ni < 4; ++ni) bh4[ni] = *(const half8*)&lds[bb + bo[ni]];
#pragma unroll
    for (int mi = 0; mi < MT; ++mi)
#pragma unroll
      for (int ni = 0; ni < 4; ++ni)
        acc[mi][ni] = MFMA_F16(ah[mi], bh4[ni], acc[mi][ni], 0, 0, 0);
    __builtin_amdgcn_s_barrier();  // all waves done reading lds[buf]
    if (k0 + 64 < K) stageAll(buf, k0 + 64);
    buf ^= 1;
  }
  if (WEMIT == 0) {
    short* C = h.C;
    float bv4[4];
#pragma unroll
    for (int ni = 0; ni < 4; ++ni) bv4[ni] = h.bias[bn + wn + ni * 16 + fr];
#pragma unroll
    for (int mi = 0; mi < MT; ++mi)
#pragma unroll
      for (int r2 = 0; r2 < 4; ++r2) {
        const int m = bm + wm + mi * 16 + fq * 4 + r2;
        float vals[4];
#pragma unroll
        for (int ni = 0; ni < 4; ++ni) vals[ni] = acc[mi][ni][r2] + bv4[ni];
        if (h.Zrow) {  // k path: store exp(logit), accumulate row sums of exp
          float es = 0.f;
#pragma unroll
          for (int ni = 0; ni < 4; ++ni) { vals[ni] = __expf(vals[ni]); es += vals[ni]; }
#pragma unroll
          for (int off = 1; off < 16; off <<= 1) es += __shfl_xor(es, off, 16);
          if (fr == 0) atomicAdd(&h.Zrow[m], es);
        }
#pragma unroll
        for (int ni = 0; ni < 4; ++ni)
          C[(size_t)m * N + bn + wn + ni * 16 + fr] = f2h(vals[ni]);
      }
  } else {
    short* C = h.C;
#pragma unroll
    for (int ni = 0; ni < 4; ++ni) {
      const int n = bn + wn + ni * 16 + fr;
#pragma unroll
      for (int mi = 0; mi < MT; ++mi) {
        const int m0 = bm + wm + mi * 16 + fq * 4;
#pragma unroll
        for (int r2 = 0; r2 < 4; ++r2)
          C[(size_t)(m0 + r2) * N + n] = f2h(acc[mi][ni][r2]);
      }
    }
  }
}

// One fused prep dispatch (4352 blocks): conversions + transposes + bias combines.
__global__ __launch_bounds__(256) void prep(
    const float* __restrict__ hs, short* hs_h, short* hs_l, short* hs_f,
    const float* __restrict__ Wfq, short* Wfq_h, short* Wfq_l,
    const float* __restrict__ Wfk, short* Wfk_f,
    const float* __restrict__ Wv, short* Wv_f,
    const float* __restrict__ Wq, short* WqT_h, short* WqT_l,
    const float* __restrict__ Wk, short* WkT_f,
    const float* __restrict__ bq, const float* __restrict__ bfq, float* bcQ,
    const float* __restrict__ bk, const float* __restrict__ bfk, float* bcK) {
  __shared__ float tb[32][33];
  const int blk = blockIdx.x, tid = threadIdx.x;
  if (blk < 1024) {
#pragma unroll
    for (int p = 0; p < 4; ++p) {
      const int i = blk * 1024 + p * 256 + tid;
      float4 v = ((const float4*)hs)[i];
      short4 hh, ll;
      split1(v.x, &hh.x, &ll.x); split1(v.y, &hh.y, &ll.y);
      split1(v.z, &hh.z, &ll.z); split1(v.w, &hh.w, &ll.w);
      ((short4*)hs_h)[i] = hh; ((short4*)hs_l)[i] = ll;
      ((short4*)hs_f)[i] = make_short4(f2h(v.x), f2h(v.y), f2h(v.z), f2h(v.w));
    }
  } else if (blk < 1280) {
    const int base = blk - 1024;
#pragma unroll
    for (int p = 0; p < 4; ++p) {
      const int i = base * 1024 + p * 256 + tid;
      float4 v = ((const float4*)Wfq)[i];
      short4 hh, ll;
      split1(v.x, &hh.x, &ll.x); split1(v.y, &hh.y, &ll.y);
      split1(v.z, &hh.z, &ll.z); split1(v.w, &hh.w, &ll.w);
      ((short4*)Wfq_h)[i] = hh; ((short4*)Wfq_l)[i] = ll;
    }
  } else if (blk < 1792) {
    const int base = blk - 1280;  // [0,512): first 256 = Wfk, next 256 = Wv
    const float* src = (base < 256) ? Wfk : Wv;
    short* dst = (base < 256) ? Wfk_f : Wv_f;
    const int bb = base & 255;
#pragma unroll
    for (int p = 0; p < 4; ++p) {
      const int i = bb * 1024 + p * 256 + tid;
      float4 v = ((const float4*)src)[i];
      ((short4*)dst)[i] = make_short4(f2h(v.x), f2h(v.y), f2h(v.z), f2h(v.w));
    }
  } else if (blk < 2816) {
    const int tt = blk - 1792;
    const int bx = (tt & 31) * 32, by = (tt >> 5) * 32;
    const int x = tid & 31, y0 = tid >> 5;
#pragma unroll
    for (int i = 0; i < 32; i += 8) tb[y0 + i][x] = Wq[(size_t)(by + y0 + i) * E + bx + x];
    __syncthreads();
#pragma unroll
    for (int i = 0; i < 32; i += 8) {
      short hh, ll;
      split1(tb[x][y0 + i], &hh, &ll);
      const size_t o = (size_t)(bx + y0 + i) * E + by + x;
      WqT_h[o] = hh; WqT_l[o] = ll;
    }
  } else if (blk < 3840) {
    const int tt = blk - 2816;
    const int bx = (tt & 31) * 32, by = (tt >> 5) * 32;
    const int x = tid & 31, y0 = tid >> 5;
#pragma unroll
    for (int i = 0; i < 32; i += 8) tb[y0 + i][x] = Wk[(size_t)(by + y0 + i) * E + bx + x];
    __syncthreads();
#pragma unroll
    for (int i = 0; i < 32; i += 8)
      WkT_f[(size_t)(bx + y0 + i) * E + by + x] = f2h(tb[x][y0 + i]);
  } else {
    const int t = blk - 3840;
    const float* Wf = (t < 256) ? Wfq : Wfk;
    const float* bin = (t < 256) ? bq : bk;
    const float* bf = (t < 256) ? bfq : bfk;
    float* o = (t < 256) ? bcQ : bcK;
    const int n = (t & 255) * 4 + (tid >> 6);
    const int lane = tid & 63;
    float sacc = 0.f;
    for (int j = lane; j < E; j += 64) sacc += Wf[(size_t)n * E + j] * bin[j];
#pragma unroll
    for (int off = 32; off; off >>= 1) sacc += __shfl_xor(sacc, off, 64);
    if (lane == 0) o[n] = sacc + bf[n];
  }
}

// Per-chunk KV partials (NO atomics — R8's device-scope atomics caused 65 MB of
// HBM RMW traffic; plain stores of partials are ~8 MB total).
// Grid (32 bh, CH=16 chunks of 128 t). KVp[(bh*CH+c)][64][64], ksump[(bh*CH+c)][64].
__global__ __launch_bounds__(256) void kv_part(const short* __restrict__ kh,
                                               const short* __restrict__ vh,
                                               const float* __restrict__ Zk,
                                               float* __restrict__ KVp,
                                               float* __restrict__ ksump) {
  const int bh = blockIdx.x;
  const int b = bh / H, h = bh % H;
  const int t0 = blockIdx.y * 128;
  const short* kbase = kh + (size_t)b * S * E + (size_t)h * D;
  const short* vbase = vh + (size_t)b * S * E + (size_t)h * D;
  __shared__ float ks[16][D];
  __shared__ float vs[16][D];
  __shared__ float invZs[128];
  const int tid = threadIdx.x;
  if (tid < 128) invZs[tid] = 1.0f / Zk[b * S + t0 + tid];  // batch offset b*S!
  const int a4 = tid & 15, b4 = tid >> 4;
  const int lt = tid >> 4, d4 = (tid & 15) * 4;  // staging: row-in-tile, d offset
  float acc[4][4] = {};
  float ksm[4] = {};
  for (int ts = 0; ts < 128; ts += 16) {
    __syncthreads();
    const size_t roff = (size_t)(t0 + ts + lt) * E + d4;
    short4 k4 = *(const short4*)(kbase + roff);
    short4 v4 = *(const short4*)(vbase + roff);
    const float iz = invZs[ts + lt];
    ks[lt][d4 + 0] = h2f(k4.x) * iz; ks[lt][d4 + 1] = h2f(k4.y) * iz;
    ks[lt][d4 + 2] = h2f(k4.z) * iz; ks[lt][d4 + 3] = h2f(k4.w) * iz;
    vs[lt][d4 + 0] = h2f(v4.x); vs[lt][d4 + 1] = h2f(v4.y);
    vs[lt][d4 + 2] = h2f(v4.z); vs[lt][d4 + 3] = h2f(v4.w);
    __syncthreads();
#pragma unroll
    for (int tt = 0; tt < 16; ++tt) {
      float kk4[4], vv4[4];
#pragma unroll
      for (int i = 0; i < 4; ++i) kk4[i] = ks[tt][a4 * 4 + i];
#pragma unroll
      for (int j = 0; j < 4; ++j) vv4[j] = vs[tt][b4 * 4 + j];
#pragma unroll
      for (int i = 0; i < 4; ++i) {
        ksm[i] += kk4[i];
#pragma unroll
        for (int j = 0; j < 4; ++j) acc[i][j] = fmaf(kk4[i], vv4[j], acc[i][j]);
      }
    }
  }
  float* kvout = KVp + ((size_t)bh * CH + blockIdx.y) * 4096;
#pragma unroll
  for (int i = 0; i < 4; ++i)
    *(float4*)&kvout[(a4 * 4 + i) * 64 + b4 * 4] =
        make_float4(acc[i][0], acc[i][1], acc[i][2], acc[i][3]);
  if (b4 == 0)
    *(float4*)&ksump[((size_t)bh * CH + blockIdx.y) * 64 + a4 * 4] =
        make_float4(ksm[0], ksm[1], ksm[2], ksm[3]);
}

// Reduce CH partials -> final KV[32][64][64], ksum[32][64]. 32 blocks.
__global__ __launch_bounds__(256) void kv_reduce(const float* __restrict__ KVp,
                                                 const float* __restrict__ ksump,
                                                 float* __restrict__ KV,
                                                 float* __restrict__ ksum) {
  const int bh = blockIdx.x, tid = threadIdx.x;
  for (int i = tid; i < 1024; i += 256) {  // float4 index within 4096
    float4 s = make_float4(0.f, 0.f, 0.f, 0.f);
#pragma unroll
    for (int c = 0; c < CH; ++c) {
      float4 p = ((const float4*)(KVp + ((size_t)bh * CH + c) * 4096))[i];
      s.x += p.x; s.y += p.y; s.z += p.z; s.w += p.w;
    }
    ((float4*)(KV + (size_t)bh * 4096))[i] = s;
  }
  if (tid < 16) {
    float4 s = make_float4(0.f, 0.f, 0.f, 0.f);
#pragma unroll
    for (int c = 0; c < CH; ++c) {
      float4 p = ((const float4*)(ksump + ((size_t)bh * CH + c) * 64))[tid];
      s.x += p.x; s.y += p.y; s.z += p.z; s.w += p.w;
    }
    ((float4*)(ksum + bh * 64))[tid] = s;
  }
}

// Output: grid (32 bh, 32 chunks of 64 rows) = 1024 blocks. KV[bh] staged in LDS once.
// Each wave: 4 rows concurrently (lane = r2*16+g; d' = g*4..+3 float4), 16 rows total.
__global__ __launch_bounds__(256) void out_v6(const float* __restrict__ qf,
                                              const float* __restrict__ KV,
                                              const float* __restrict__ ksum,
                                              float* __restrict__ out) {
  const int bh = blockIdx.x;
  const int b = bh >> 4, h = bh & 15;
  __shared__ float KVs[64][64];  // LD=64: float4 reads are 2-way bank-aliased (free)
  __shared__ float kss[64];
  __shared__ float qs[4][4][64];
  const int tid = threadIdx.x, wave = tid >> 6, lane = tid & 63;
  const int r2 = lane >> 4, g = lane & 15;
  for (int i = tid; i < 1024; i += 256)
    ((float4*)KVs)[i] = ((const float4*)(KV + (size_t)bh * 4096))[i];
  if (tid < 64) kss[tid] = ksum[bh * 64 + tid];
  __syncthreads();
  const float4 ks4 = *(const float4*)&kss[g * 4];
  const int row0 = blockIdx.y * 64 + wave * 16;
#pragma unroll
  for (int it = 0; it < 4; ++it) {
    const int row = row0 + it * 4 + r2;
    const size_t rowoff = ((size_t)b * S + row) * E + h * 64;
    float4 u = *(const float4*)(qf + rowoff + g * 4);
    u.x = __expf(u.x); u.y = __expf(u.y); u.z = __expf(u.z); u.w = __expf(u.w);
    float dn = u.x * ks4.x + u.y * ks4.y + u.z * ks4.z + u.w * ks4.w;
#pragma unroll
    for (int off = 1; off < 16; off <<= 1) dn += __shfl_xor(dn, off, 16);
    *(float4*)&qs[wave][r2][g * 4] = u;
    __syncthreads();  // publish qs (uniform: all waves run 4 iters)
    float nx = 0.f, ny = 0.f, nz = 0.f, nw = 0.f;
#pragma unroll
    for (int d = 0; d < 64; ++d) {
      const float qd = qs[wave][r2][d];
      const float4 kv = *(const float4*)&KVs[d][g * 4];
      nx = fmaf(qd, kv.x, nx); ny = fmaf(qd, kv.y, ny);
      nz = fmaf(qd, kv.z, nz); nw = fmaf(qd, kv.w, nw);
    }
    const float inv = 1.0f / dn;
    float4 o4 = make_float4(nx * inv, ny * inv, nz * inv, nw * inv);
    *(float4*)(out + rowoff + g * 4) = o4;
    __syncthreads();  // qs reused next iteration
  }
}

extern "C" void kernel_launch(void* const* d_in, const int* in_sizes, int n_in,
                              void* d_out, int out_size, void* d_ws, size_t ws_size,
                              hipStream_t stream) {
  const float* hs = (const float*)d_in[0];
  const float* Wq = (const float*)d_in[1];
  const float* bq = (const float*)d_in[2];
  const float* Wk = (const float*)d_in[3];
  const float* bk = (const float*)d_in[4];
  const float* Wv = (const float*)d_in[5];
  const float* bv = (const float*)d_in[6];
  const float* Wfq = (const float*)d_in[7];
  const float* bfq = (const float*)d_in[8];
  const float* Wfk = (const float*)d_in[9];
  const float* bfk = (const float*)d_in[10];
  float* out = (float*)d_out;

  const size_t MEG = 1024 * 1024;
  float* ws = (float*)d_ws;
  float* qf = ws;                                       // [M,E] fp32 q logits (16 MB)
  short* kh = (short*)(ws + 4 * MEG);                   // [M,E] fp16 e=exp(k logit) (8 MB)
  short* vh = (short*)(ws + 6 * MEG);                   // [M,E] fp16 v (8 MB)
  short* hs_h = (short*)(ws + 8 * MEG);                 // bf16 hi (8 MB)
  short* hs_l = (short*)(ws + 10 * MEG);                // bf16 lo (8 MB)
  short* hs_f = (short*)(ws + 12 * MEG);                // fp16 (8 MB)
  short* Wfq_h = (short*)(ws + 14 * MEG);
  short* Wfq_l = (short*)(ws + 14 * MEG + 512 * 1024);
  short* WqT_h = (short*)(ws + 15 * MEG);
  short* WqT_l = (short*)(ws + 15 * MEG + 512 * 1024);
  short* Wfk_f = (short*)(ws + 16 * MEG);
  short* WkT_f = (short*)(ws + 16 * MEG + 512 * 1024);
  short* Wv_f = (short*)(ws + 17 * MEG);
  short* WcQ_h = (short*)(ws + 17 * MEG + 512 * 1024);
  short* WcQ_l = (short*)(ws + 18 * MEG);
  short* WcK_f = (short*)(ws + 18 * MEG + 512 * 1024);
  float* bcQ = ws + 19 * MEG;
  float* bcK = bcQ + 1024;
  float* Zk = bcK + 1024;                               // [M]
  float* KV = Zk + M;                                   // [32][64][64]
  float* ksum = KV + 32 * 4096;                         // [32][64]
  // KV partials alias hs_h/hs_l (dead after big GEMM): 32*CH*4096 = 8 MB + 128 KB
  float* KVp = (float*)hs_h;
  float* ksump = (float*)hs_l;

  // 0) Zero Zk accumulator (16 KB).
  hipMemsetAsync(Zk, 0, M * sizeof(float), stream);
  // 1) Fused prep: conversions + transposes + bias combines.
  prep<<<4352, 256, 0, stream>>>(hs, hs_h, hs_l, hs_f,
                                 Wfq, Wfq_h, Wfq_l, Wfk, Wfk_f, Wv, Wv_f,
                                 Wq, WqT_h, WqT_l, Wk, WkT_f,
                                 bq, bfq, bcQ, bk, bfk, bcK);
  // 2) Combined weights: z=0 split WcQ = Wfq@Wq, z=1 fp16 WcK = Wfk@Wk.
  SArgs sw = {Wfq_h, Wfq_l, WqT_h, WqT_l, nullptr, nullptr, WcQ_h, WcQ_l};
  HArgs hw = {Wfk_f, WkT_f, nullptr, WcK_f, nullptr};
  gemm_combo<64, 1><<<dim3(16, 8, 2), 256, 0, stream>>>(sw, hw, hw, E, E);
  // 3) Big GEMM: z=0 split q logits (fp32); z=1 fp16 k -> exp stored fp16 + Zk; z=2 fp16 v.
  SArgs sb = {hs_h, hs_l, WcQ_h, WcQ_l, bcQ, qf, nullptr, nullptr};
  HArgs hk = {hs_f, WcK_f, bcK, kh, Zk};
  HArgs hv = {hs_f, Wv_f, bv, vh, nullptr};
  gemm_combo<128, 0><<<dim3(32, 8, 3), 256, 0, stream>>>(sb, hk, hv, E, E);
  // 4) KV partials (512 blocks, plain stores into aliased hs_h/hs_l region).
  kv_part<<<dim3(B * H, CH), 256, 0, stream>>>(kh, vh, Zk, KVp, ksump);
  // 5) Reduce partials -> KV, ksum (32 blocks).
  kv_reduce<<<B * H, 256, 0, stream>>>(KVp, ksump, KV, ksum);
  // 6) Output (1024 blocks; exp applied inline; q normalization cancels).
  out_v6<<<dim3(B * H, S / 64), 256, 0, stream>>>(qf, KV, ksum, out);
}

// Round 10
// 189.020 us; speedup vs baseline: 1.4232x; 1.1695x over previous
//
#include <hip/hip_runtime.h>
#include <math.h>

constexpr int B = 2, S = 2048, E = 1024, H = 16, D = 64;
constexpr int M = B * S;  // 4096
constexpr int CH = 16;    // kv chunks per (b,h), 128 t each

typedef __attribute__((ext_vector_type(8))) _Float16 half8;
typedef __attribute__((ext_vector_type(4))) float f32x4;
#define MFMA_F16 __builtin_amdgcn_mfma_f32_16x16x32_f16
// wait until at most N vector-memory ops outstanding; leave lgkm/exp unconstrained
#define WAITCNT_VM(N) __builtin_amdgcn_s_waitcnt(0xF70 | (N))

__device__ __forceinline__ short f2h(float f) {
  _Float16 h = (_Float16)f;
  short s;
  __builtin_memcpy(&s, &h, 2);
  return s;
}
__device__ __forceinline__ float h2f(short s) {
  _Float16 h;
  __builtin_memcpy(&h, &s, 2);
  return (float)h;
}

// Async global->LDS DMA, 16B per lane. LDS dest = wave-uniform base + lane*16.
__device__ __forceinline__ void gload16(const void* g, const void* l) {
  __builtin_amdgcn_global_load_lds(
      (const __attribute__((address_space(1))) unsigned*)g,
      (__attribute__((address_space(3))) unsigned*)l, 16, 0, 0);
}

struct HArgs {
  const short* A;   // [Mrows x K] fp16 bits, row-major
  const short* Bm;  // [N x K] fp16 bits, row-major
  const float* bias;  // WEMIT=0 only
  short* C;           // fp16 out
  float* Zrow;        // WEMIT=0 optional: += rowsum of stored values (after exp)
  int doExp;          // WEMIT=0: store exp(val) instead of val
};

// C[m,n] = f16(sum_k A[m,k]*B[n,k] [+bias] [exp]), fp16 MFMA, fp32 accumulate.
// BM in {64,128}, BN=128, 256 threads = 4 waves (2x2); pipelined: double LDS
// buffer, raw s_barrier, s_waitcnt vmcnt(PW) mid-loop (prefetch stays in flight).
template <int BM, int WEMIT>
__global__ __launch_bounds__(256, 3) void gemmh(HArgs g0, HArgs g1, HArgs g2, int K, int N) {
  const HArgs h = (blockIdx.z == 0) ? g0 : (blockIdx.z == 1 ? g1 : g2);
  constexpr int SA = BM / 16;      // A staging segments (1KB each)
  constexpr int TOT = SA + 8;      // + 8 B segments
  constexpr int PW = TOT / 4;      // staging instructions per wave
  constexpr int MT = BM / 32;      // m-tiles per wave
  __shared__ short lds[2][TOT * 512];

  const int tid = threadIdx.x, wave = tid >> 6, lane = tid & 63;
  const int bm = blockIdx.x * BM, bn = blockIdx.y * 128;

  // staging addresses: instruction n = wave*PW+j covers 16 rows of A or B tile
  const short* gb[PW];
#pragma unroll
  for (int j = 0; j < PW; ++j) {
    const int n = wave * PW + j;
    const short* src; int seg, rowbase;
    if (n < SA) { src = h.A;  seg = n;      rowbase = bm; }
    else        { src = h.Bm; seg = n - SA; rowbase = bn; }
    const int r = seg * 16 + (lane >> 2);   // row within tile
    const int p = lane & 3;                 // LDS chunk slot this lane fills
    const int q = (p - ((r >> 1) & 3)) & 3; // k-chunk that belongs in slot p (swizzle)
    gb[j] = src + (size_t)(rowbase + r) * K + q * 8;
  }

  // fragment read offsets (swizzled chunks -> conflict-free ds_read_b128)
  const int fr = lane & 15, fq = lane >> 4;
  const int wm = (wave & 1) * (BM / 2), wn = (wave >> 1) * 64;
  int ao[MT], bo[4];
#pragma unroll
  for (int mi = 0; mi < MT; ++mi) {
    const int r = wm + mi * 16 + fr;
    ao[mi] = r * 32 + (((fq + ((r >> 1) & 3)) & 3)) * 8;
  }
#pragma unroll
  for (int ni = 0; ni < 4; ++ni) {
    const int r = wn + ni * 16 + fr;
    bo[ni] = BM * 32 + r * 32 + (((fq + ((r >> 1) & 3)) & 3)) * 8;
  }

  f32x4 acc[MT][4] = {};
  const int ldsW = wave * PW * 512;

  auto stageAll = [&](int buf, int k0) {
#pragma unroll
    for (int j = 0; j < PW; ++j)
      gload16(gb[j] + k0, &lds[buf][ldsW + j * 512]);
  };

  stageAll(0, 0);
  stageAll(1, 32);
  int buf = 0;
  for (int k0 = 0; k0 < K; k0 += 32) {
    if (k0 + 32 < K) WAITCNT_VM(PW); else WAITCNT_VM(0);
    __builtin_amdgcn_s_barrier();
    half8 ah[MT], bh4[4];
#pragma unroll
    for (int mi = 0; mi < MT; ++mi) ah[mi] = *(const half8*)&lds[buf][ao[mi]];
#pragma unroll
    for (int ni = 0; ni < 4; ++ni) bh4[ni] = *(const half8*)&lds[buf][bo[ni]];
#pragma unroll
    for (int mi = 0; mi < MT; ++mi)
#pragma unroll
      for (int ni = 0; ni < 4; ++ni)
        acc[mi][ni] = MFMA_F16(ah[mi], bh4[ni], acc[mi][ni], 0, 0, 0);
    __builtin_amdgcn_s_barrier();  // all waves done reading lds[buf]
    if (k0 + 64 < K) stageAll(buf, k0 + 64);
    buf ^= 1;
  }

  // epilogue: C/D layout col=lane&15, row=(lane>>4)*4+reg
  if (WEMIT == 0) {
    short* C = h.C;
    float bv4[4];
#pragma unroll
    for (int ni = 0; ni < 4; ++ni) bv4[ni] = h.bias[bn + wn + ni * 16 + fr];
#pragma unroll
    for (int mi = 0; mi < MT; ++mi)
#pragma unroll
      for (int r2 = 0; r2 < 4; ++r2) {
        const int m = bm + wm + mi * 16 + fq * 4 + r2;
        float vals[4];
#pragma unroll
        for (int ni = 0; ni < 4; ++ni) vals[ni] = acc[mi][ni][r2] + bv4[ni];
        if (h.doExp) {
#pragma unroll
          for (int ni = 0; ni < 4; ++ni) vals[ni] = __expf(vals[ni]);
        }
        if (h.Zrow) {  // k path: accumulate row sums of exp
          float es = vals[0] + vals[1] + vals[2] + vals[3];
#pragma unroll
          for (int off = 1; off < 16; off <<= 1) es += __shfl_xor(es, off, 16);
          if (fr == 0) atomicAdd(&h.Zrow[m], es);
        }
#pragma unroll
        for (int ni = 0; ni < 4; ++ni)
          C[(size_t)m * N + bn + wn + ni * 16 + fr] = f2h(vals[ni]);
      }
  } else {
    short* C = h.C;
#pragma unroll
    for (int ni = 0; ni < 4; ++ni) {
      const int n = bn + wn + ni * 16 + fr;
#pragma unroll
      for (int mi = 0; mi < MT; ++mi) {
        const int m0 = bm + wm + mi * 16 + fq * 4;
#pragma unroll
        for (int r2 = 0; r2 < 4; ++r2)
          C[(size_t)(m0 + r2) * N + n] = f2h(acc[mi][ni][r2]);
      }
    }
  }
}

// One fused prep dispatch (4353 blocks):
//   [0,1024)    hs -> fp16
//   [1024,1792) {Wfq,Wfk,Wv} -> fp16
//   [1792,3840) transpose {Wq,Wk} -> fp16
//   [3840,4352) bias combine bc = Wf @ b + bf (fp32)
//   4352        zero Zk
__global__ __launch_bounds__(256) void prep(
    const float* __restrict__ hs, short* hs_f,
    const float* __restrict__ Wfq, short* Wfq_f,
    const float* __restrict__ Wfk, short* Wfk_f,
    const float* __restrict__ Wv, short* Wv_f,
    const float* __restrict__ Wq, short* WqT_f,
    const float* __restrict__ Wk, short* WkT_f,
    const float* __restrict__ bq, const float* __restrict__ bfq, float* bcQ,
    const float* __restrict__ bk, const float* __restrict__ bfk, float* bcK,
    float* Zk) {
  __shared__ float tb[32][33];
  const int blk = blockIdx.x, tid = threadIdx.x;
  if (blk < 1024) {
#pragma unroll
    for (int p = 0; p < 4; ++p) {
      const int i = blk * 1024 + p * 256 + tid;  // float4 index
      float4 v = ((const float4*)hs)[i];
      ((short4*)hs_f)[i] = make_short4(f2h(v.x), f2h(v.y), f2h(v.z), f2h(v.w));
    }
  } else if (blk < 1792) {
    const int base = blk - 1024;  // [0,768): 256 each Wfq, Wfk, Wv
    const float* src = (base < 256) ? Wfq : (base < 512 ? Wfk : Wv);
    short* dst = (base < 256) ? Wfq_f : (base < 512 ? Wfk_f : Wv_f);
    const int bb = base & 255;
#pragma unroll
    for (int p = 0; p < 4; ++p) {
      const int i = bb * 1024 + p * 256 + tid;
      float4 v = ((const float4*)src)[i];
      ((short4*)dst)[i] = make_short4(f2h(v.x), f2h(v.y), f2h(v.z), f2h(v.w));
    }
  } else if (blk < 3840) {
    const int t = blk - 1792;
    const float* in = (t < 1024) ? Wq : Wk;
    short* oh = (t < 1024) ? WqT_f : WkT_f;
    const int tt = t & 1023;
    const int bx = (tt & 31) * 32, by = (tt >> 5) * 32;
    const int x = tid & 31, y0 = tid >> 5;
#pragma unroll
    for (int i = 0; i < 32; i += 8) tb[y0 + i][x] = in[(size_t)(by + y0 + i) * E + bx + x];
    __syncthreads();
#pragma unroll
    for (int i = 0; i < 32; i += 8)
      oh[(size_t)(bx + y0 + i) * E + by + x] = f2h(tb[x][y0 + i]);
  } else if (blk < 4352) {
    const int t = blk - 3840;
    const float* Wf = (t < 256) ? Wfq : Wfk;
    const float* bin = (t < 256) ? bq : bk;
    const float* bf = (t < 256) ? bfq : bfk;
    float* o = (t < 256) ? bcQ : bcK;
    const int n = (t & 255) * 4 + (tid >> 6);
    const int lane = tid & 63;
    float sacc = 0.f;
    for (int j = lane; j < E; j += 64) sacc += Wf[(size_t)n * E + j] * bin[j];
#pragma unroll
    for (int off = 32; off; off >>= 1) sacc += __shfl_xor(sacc, off, 64);
    if (lane == 0) o[n] = sacc + bf[n];
  } else {
    // zero Zk (4096 floats)
#pragma unroll
    for (int p = 0; p < 4; ++p)
      ((float4*)Zk)[p * 256 + tid] = make_float4(0.f, 0.f, 0.f, 0.f);
  }
}

// Per-chunk KV partials (plain stores; atomics regressed in R8: 65 MB HBM RMW).
// Grid (32 bh, CH=16 chunks of 128 t). KVp[(bh*CH+c)][64][64], ksump[(bh*CH+c)][64].
__global__ __launch_bounds__(256) void kv_part(const short* __restrict__ kh,
                                               const short* __restrict__ vh,
                                               const float* __restrict__ Zk,
                                               float* __restrict__ KVp,
                                               float* __restrict__ ksump) {
  const int bh = blockIdx.x;
  const int b = bh / H, h = bh % H;
  const int t0 = blockIdx.y * 128;
  const short* kbase = kh + (size_t)b * S * E + (size_t)h * D;
  const short* vbase = vh + (size_t)b * S * E + (size_t)h * D;
  __shared__ float ks[16][D];
  __shared__ float vs[16][D];
  __shared__ float invZs[128];
  const int tid = threadIdx.x;
  if (tid < 128) invZs[tid] = 1.0f / Zk[b * S + t0 + tid];  // batch offset b*S!
  const int a4 = tid & 15, b4 = tid >> 4;
  const int lt = tid >> 4, d4 = (tid & 15) * 4;  // staging: row-in-tile, d offset
  float acc[4][4] = {};
  float ksm[4] = {};
  for (int ts = 0; ts < 128; ts += 16) {
    __syncthreads();
    const size_t roff = (size_t)(t0 + ts + lt) * E + d4;
    short4 k4 = *(const short4*)(kbase + roff);
    short4 v4 = *(const short4*)(vbase + roff);
    const float iz = invZs[ts + lt];
    ks[lt][d4 + 0] = h2f(k4.x) * iz; ks[lt][d4 + 1] = h2f(k4.y) * iz;
    ks[lt][d4 + 2] = h2f(k4.z) * iz; ks[lt][d4 + 3] = h2f(k4.w) * iz;
    vs[lt][d4 + 0] = h2f(v4.x); vs[lt][d4 + 1] = h2f(v4.y);
    vs[lt][d4 + 2] = h2f(v4.z); vs[lt][d4 + 3] = h2f(v4.w);
    __syncthreads();
#pragma unroll
    for (int tt = 0; tt < 16; ++tt) {
      float kk4[4], vv4[4];
#pragma unroll
      for (int i = 0; i < 4; ++i) kk4[i] = ks[tt][a4 * 4 + i];
#pragma unroll
      for (int j = 0; j < 4; ++j) vv4[j] = vs[tt][b4 * 4 + j];
#pragma unroll
      for (int i = 0; i < 4; ++i) {
        ksm[i] += kk4[i];
#pragma unroll
        for (int j = 0; j < 4; ++j) acc[i][j] = fmaf(kk4[i], vv4[j], acc[i][j]);
      }
    }
  }
  float* kvout = KVp + ((size_t)bh * CH + blockIdx.y) * 4096;
#pragma unroll
  for (int i = 0; i < 4; ++i)
    *(float4*)&kvout[(a4 * 4 + i) * 64 + b4 * 4] =
        make_float4(acc[i][0], acc[i][1], acc[i][2], acc[i][3]);
  if (b4 == 0)
    *(float4*)&ksump[((size_t)bh * CH + blockIdx.y) * 64 + a4 * 4] =
        make_float4(ksm[0], ksm[1], ksm[2], ksm[3]);
}

// Reduce CH partials -> final KV[32][64][64], ksum[32][64]. 32 blocks.
__global__ __launch_bounds__(256) void kv_reduce(const float* __restrict__ KVp,
                                                 const float* __restrict__ ksump,
                                                 float* __restrict__ KV,
                                                 float* __restrict__ ksum) {
  const int bh = blockIdx.x, tid = threadIdx.x;
  for (int i = tid; i < 1024; i += 256) {  // float4 index within 4096
    float4 s = make_float4(0.f, 0.f, 0.f, 0.f);
#pragma unroll
    for (int c = 0; c < CH; ++c) {
      float4 p = ((const float4*)(KVp + ((size_t)bh * CH + c) * 4096))[i];
      s.x += p.x; s.y += p.y; s.z += p.z; s.w += p.w;
    }
    ((float4*)(KV + (size_t)bh * 4096))[i] = s;
  }
  if (tid < 16) {
    float4 s = make_float4(0.f, 0.f, 0.f, 0.f);
#pragma unroll
    for (int c = 0; c < CH; ++c) {
      float4 p = ((const float4*)(ksump + ((size_t)bh * CH + c) * 64))[tid];
      s.x += p.x; s.y += p.y; s.z += p.z; s.w += p.w;
    }
    ((float4*)(ksum + bh * 64))[tid] = s;
  }
}

// Output: grid (32 bh, 32 chunks of 64 rows) = 1024 blocks. KV[bh] staged in LDS.
// u = stored exp(q logit) fp16 (q softmax normalization cancels in the ratio).
__global__ __launch_bounds__(256) void out_v7(const short* __restrict__ uh,
                                              const float* __restrict__ KV,
                                              const float* __restrict__ ksum,
                                              float* __restrict__ out) {
  const int bh = blockIdx.x;
  const int b = bh >> 4, h = bh & 15;
  __shared__ float KVs[64][64];  // LD=64: float4 reads are 2-way bank-aliased (free)
  __shared__ float kss[64];
  __shared__ float qs[4][4][64];
  const int tid = threadIdx.x, wave = tid >> 6, lane = tid & 63;
  const int r2 = lane >> 4, g = lane & 15;
  for (int i = tid; i < 1024; i += 256)
    ((float4*)KVs)[i] = ((const float4*)(KV + (size_t)bh * 4096))[i];
  if (tid < 64) kss[tid] = ksum[bh * 64 + tid];
  __syncthreads();
  const float4 ks4 = *(const float4*)&kss[g * 4];
  const int row0 = blockIdx.y * 64 + wave * 16;
#pragma unroll
  for (int it = 0; it < 4; ++it) {
    const int row = row0 + it * 4 + r2;
    const size_t rowoff = ((size_t)b * S + row) * E + h * 64;
    short4 us = *(const short4*)(uh + rowoff + g * 4);
    float4 u = make_float4(h2f(us.x), h2f(us.y), h2f(us.z), h2f(us.w));
    float dn = u.x * ks4.x + u.y * ks4.y + u.z * ks4.z + u.w * ks4.w;
#pragma unroll
    for (int off = 1; off < 16; off <<= 1) dn += __shfl_xor(dn, off, 16);
    *(float4*)&qs[wave][r2][g * 4] = u;
    __syncthreads();  // publish qs (uniform: all waves run 4 iters)
    float nx = 0.f, ny = 0.f, nz = 0.f, nw = 0.f;
#pragma unroll
    for (int d = 0; d < 64; ++d) {
      const float qd = qs[wave][r2][d];
      const float4 kv = *(const float4*)&KVs[d][g * 4];
      nx = fmaf(qd, kv.x, nx); ny = fmaf(qd, kv.y, ny);
      nz = fmaf(qd, kv.z, nz); nw = fmaf(qd, kv.w, nw);
    }
    const float inv = 1.0f / dn;
    float4 o4 = make_float4(nx * inv, ny * inv, nz * inv, nw * inv);
    *(float4*)(out + rowoff + g * 4) = o4;
    __syncthreads();  // qs reused next iteration
  }
}

extern "C" void kernel_launch(void* const* d_in, const int* in_sizes, int n_in,
                              void* d_out, int out_size, void* d_ws, size_t ws_size,
                              hipStream_t stream) {
  const float* hs = (const float*)d_in[0];
  const float* Wq = (const float*)d_in[1];
  const float* bq = (const float*)d_in[2];
  const float* Wk = (const float*)d_in[3];
  const float* bk = (const float*)d_in[4];
  const float* Wv = (const float*)d_in[5];
  const float* bv = (const float*)d_in[6];
  const float* Wfq = (const float*)d_in[7];
  const float* bfq = (const float*)d_in[8];
  const float* Wfk = (const float*)d_in[9];
  const float* bfk = (const float*)d_in[10];
  float* out = (float*)d_out;

  const size_t MEG = 1024 * 1024;
  float* ws = (float*)d_ws;
  short* uh = (short*)ws;                     // [M,E] fp16 exp(q logit) (8 MB)
  short* kh = (short*)(ws + 2 * MEG);         // [M,E] fp16 exp(k logit) (8 MB)
  short* vh = (short*)(ws + 4 * MEG);         // [M,E] fp16 v (8 MB)
  short* hs_f = (short*)(ws + 6 * MEG);       // [M,E] fp16 hs (8 MB; dead after big GEMM)
  short* Wfq_f = (short*)(ws + 8 * MEG);      // 2 MB each (dead after wgemm)
  short* Wfk_f = (short*)(ws + 8 * MEG + 512 * 1024);
  short* Wv_f = (short*)(ws + 9 * MEG);
  short* WqT_f = (short*)(ws + 9 * MEG + 512 * 1024);
  short* WkT_f = (short*)(ws + 10 * MEG);
  short* WcQ_f = (short*)(ws + 10 * MEG + 512 * 1024);
  short* WcK_f = (short*)(ws + 11 * MEG);
  float* bcQ = ws + 12 * MEG;
  float* bcK = bcQ + 1024;
  float* Zk = bcK + 1024;                     // [M]
  float* KV = Zk + M;                         // [32][64][64]
  float* ksum = KV + 32 * 4096;               // [32][64]
  // KV partials alias hs_f (exactly 8 MB, dead after big GEMM); ksump after Wfq_f:
  float* KVp = (float*)hs_f;                  // 32*CH*4096 floats = 8 MB
  float* ksump = (float*)Wfq_f;               // 32*CH*64 floats = 128 KB

  // 1) Fused prep: fp16 conversions + transposes + bias combines + Zk zero.
  prep<<<4353, 256, 0, stream>>>(hs, hs_f, Wfq, Wfq_f, Wfk, Wfk_f, Wv, Wv_f,
                                 Wq, WqT_f, Wk, WkT_f,
                                 bq, bfq, bcQ, bk, bfk, bcK, Zk);
  // 2) Combined weights: WcQ = Wfq@Wq, WcK = Wfk@Wk (fp16, z-batched).
  HArgs w0 = {Wfq_f, WqT_f, nullptr, WcQ_f, nullptr, 0};
  HArgs w1 = {Wfk_f, WkT_f, nullptr, WcK_f, nullptr, 0};
  gemmh<64, 1><<<dim3(16, 8, 2), 256, 0, stream>>>(w0, w1, w1, E, E);
  // 3) Big GEMM (3 uniform fp16 slices): z=0 q -> exp stored fp16;
  //    z=1 k -> exp stored fp16 + Zk rowsums; z=2 v -> fp16.
  HArgs gq = {hs_f, WcQ_f, bcQ, uh, nullptr, 1};
  HArgs gk = {hs_f, WcK_f, bcK, kh, Zk, 1};
  HArgs gv = {hs_f, Wv_f, bv, vh, nullptr, 0};
  gemmh<128, 0><<<dim3(32, 8, 3), 256, 0, stream>>>(gq, gk, gv, E, E);
  // 4) KV partials (512 blocks, plain stores into aliased regions).
  kv_part<<<dim3(B * H, CH), 256, 0, stream>>>(kh, vh, Zk, KVp, ksump);
  // 5) Reduce partials -> KV, ksum (32 blocks).
  kv_reduce<<<B * H, 256, 0, stream>>>(KVp, ksump, KV, ksum);
  // 6) Output (1024 blocks).
  out_v7<<<dim3(B * H, S / 64), 256, 0, stream>>>(uh, KV, ksum, out);
}

// Round 11
// 182.519 us; speedup vs baseline: 1.4739x; 1.0356x over previous
//
#include <hip/hip_runtime.h>
#include <math.h>

constexpr int B = 2, S = 2048, E = 1024, H = 16, D = 64;
constexpr int M = B * S;   // 4096
constexpr int NBIG = 3072; // fused q|k|v output width
constexpr int CH = 8;      // kv chunks per (b,h), 256 t each

typedef __attribute__((ext_vector_type(8))) _Float16 half8;
typedef __attribute__((ext_vector_type(4))) float f32x4;
#define MFMA_F16 __builtin_amdgcn_mfma_f32_16x16x32_f16
// wait until at most N vector-memory ops outstanding; leave lgkm/exp unconstrained
#define WAITCNT_VM(N) __builtin_amdgcn_s_waitcnt(0xF70 | (N))

__device__ __forceinline__ short f2h(float f) {
  _Float16 h = (_Float16)f;
  short s;
  __builtin_memcpy(&s, &h, 2);
  return s;
}
__device__ __forceinline__ float h2f(short s) {
  _Float16 h;
  __builtin_memcpy(&h, &s, 2);
  return (float)h;
}

// Async global->LDS DMA, 16B per lane. LDS dest = wave-uniform base + lane*16.
__device__ __forceinline__ void gload16(const void* g, const void* l) {
  __builtin_amdgcn_global_load_lds(
      (const __attribute__((address_space(1))) unsigned*)g,
      (__attribute__((address_space(3))) unsigned*)l, 16, 0, 0);
}

// Pipelined fp16 NT-GEMM core: acc[m][n] += A[bm+..][k]*B[bn+..][k] over K.
// BM in {64,128}, BN=128 fixed, 4 waves (2x2), swizzled LDS chunks, double buffer,
// raw s_barrier + s_waitcnt vmcnt(PW) mid-loop (prefetch stays in flight).
template <int BM>
__device__ __forceinline__ void gemm_core(const short* __restrict__ A,
                                          const short* __restrict__ Bm,
                                          int bm, int bn, int K, short* lds,
                                          f32x4 (&acc)[BM / 32][4]) {
  constexpr int SA = BM / 16, TOT = SA + 8, PW = TOT / 4, MT = BM / 32;
  const int tid = threadIdx.x, wave = tid >> 6, lane = tid & 63;

  const short* gb[PW];
#pragma unroll
  for (int j = 0; j < PW; ++j) {
    const int n = wave * PW + j;
    const short* src; int seg, rowbase;
    if (n < SA) { src = A;  seg = n;      rowbase = bm; }
    else        { src = Bm; seg = n - SA; rowbase = bn; }
    const int r = seg * 16 + (lane >> 2);   // row within tile
    const int p = lane & 3;                 // LDS chunk slot this lane fills
    const int q = (p - ((r >> 1) & 3)) & 3; // k-chunk that belongs in slot p (swizzle)
    gb[j] = src + (size_t)(rowbase + r) * K + q * 8;
  }
  const int fr = lane & 15, fq = lane >> 4;
  const int wm = (wave & 1) * (BM / 2), wn = (wave >> 1) * 64;
  int ao[MT], bo[4];
#pragma unroll
  for (int mi = 0; mi < MT; ++mi) {
    const int r = wm + mi * 16 + fr;
    ao[mi] = r * 32 + (((fq + ((r >> 1) & 3)) & 3)) * 8;
  }
#pragma unroll
  for (int ni = 0; ni < 4; ++ni) {
    const int r = wn + ni * 16 + fr;
    bo[ni] = BM * 32 + r * 32 + (((fq + ((r >> 1) & 3)) & 3)) * 8;
  }
  const int ldsW = wave * PW * 512;
  auto stageAll = [&](int buf, int k0) {
#pragma unroll
    for (int j = 0; j < PW; ++j)
      gload16(gb[j] + k0, &lds[buf * TOT * 512 + ldsW + j * 512]);
  };
  stageAll(0, 0);
  stageAll(1, 32);
  int buf = 0;
  for (int k0 = 0; k0 < K; k0 += 32) {
    if (k0 + 32 < K) WAITCNT_VM(PW); else WAITCNT_VM(0);
    __builtin_amdgcn_s_barrier();
    half8 ah[MT], bh4[4];
    const int bb = buf * TOT * 512;
#pragma unroll
    for (int mi = 0; mi < MT; ++mi) ah[mi] = *(const half8*)&lds[bb + ao[mi]];
#pragma unroll
    for (int ni = 0; ni < 4; ++ni) bh4[ni] = *(const half8*)&lds[bb + bo[ni]];
#pragma unroll
    for (int mi = 0; mi < MT; ++mi)
#pragma unroll
      for (int ni = 0; ni < 4; ++ni)
        acc[mi][ni] = MFMA_F16(ah[mi], bh4[ni], acc[mi][ni], 0, 0, 0);
    __builtin_amdgcn_s_barrier();  // all waves done reading lds[buf]
    if (k0 + 64 < K) stageAll(buf, k0 + 64);
    buf ^= 1;
  }
}

// prep_w (3329 blocks): weight fp16 conversions + transposes + bias combines +
// bv copy + Zk zero. (hs conversion moved into the wgemm dispatch.)
__global__ __launch_bounds__(256) void prep_w(
    const float* __restrict__ Wfq, short* Wfq_f,
    const float* __restrict__ Wfk, short* Wfk_f,
    const float* __restrict__ Wv, short* Wv_f,
    const float* __restrict__ Wq, short* WqT_f,
    const float* __restrict__ Wk, short* WkT_f,
    const float* __restrict__ bq, const float* __restrict__ bfq,
    const float* __restrict__ bk, const float* __restrict__ bfk,
    const float* __restrict__ bv, float* bcat, float* Zk) {
  __shared__ float tb[32][33];
  const int blk = blockIdx.x, tid = threadIdx.x;
  if (blk < 768) {
    const int base = blk;  // 256 each: Wfq, Wfk, Wv
    const float* src = (base < 256) ? Wfq : (base < 512 ? Wfk : Wv);
    short* dst = (base < 256) ? Wfq_f : (base < 512 ? Wfk_f : Wv_f);
    const int bb = base & 255;
#pragma unroll
    for (int p = 0; p < 4; ++p) {
      const int i = bb * 1024 + p * 256 + tid;  // float4 index
      float4 v = ((const float4*)src)[i];
      ((short4*)dst)[i] = make_short4(f2h(v.x), f2h(v.y), f2h(v.z), f2h(v.w));
    }
  } else if (blk < 2816) {
    const int t = blk - 768;
    const float* in = (t < 1024) ? Wq : Wk;
    short* oh = (t < 1024) ? WqT_f : WkT_f;
    const int tt = t & 1023;
    const int bx = (tt & 31) * 32, by = (tt >> 5) * 32;
    const int x = tid & 31, y0 = tid >> 5;
#pragma unroll
    for (int i = 0; i < 32; i += 8) tb[y0 + i][x] = in[(size_t)(by + y0 + i) * E + bx + x];
    __syncthreads();
#pragma unroll
    for (int i = 0; i < 32; i += 8)
      oh[(size_t)(bx + y0 + i) * E + by + x] = f2h(tb[x][y0 + i]);
  } else if (blk < 3328) {
    const int t = blk - 2816;
    const float* Wf = (t < 256) ? Wfq : Wfk;
    const float* bin = (t < 256) ? bq : bk;
    const float* bf = (t < 256) ? bfq : bfk;
    float* o = (t < 256) ? bcat : bcat + 1024;
    const int n = (t & 255) * 4 + (tid >> 6);
    const int lane = tid & 63;
    float sacc = 0.f;
    for (int j = lane; j < E; j += 64) sacc += Wf[(size_t)n * E + j] * bin[j];
#pragma unroll
    for (int off = 32; off; off >>= 1) sacc += __shfl_xor(sacc, off, 64);
    if (lane == 0) o[n] = sacc + bf[n];
  } else {
    // copy bv -> bcat[2048..3072) and zero Zk[4096]
    ((float4*)(bcat + 2048))[tid] = ((const float4*)bv)[tid];
#pragma unroll
    for (int p = 0; p < 4; ++p)
      ((float4*)Zk)[p * 256 + tid] = make_float4(0.f, 0.f, 0.f, 0.f);
  }
}

// Weight-combine GEMMs (z=0: WcQ = Wfq@Wq, z=1: WcK = Wfk@Wk) + hs fp16
// conversion as z=2 (fills the otherwise 256-block latency-bound dispatch).
__global__ __launch_bounds__(256, 3) void wgemm_hs(
    const short* __restrict__ Wfq_f, const short* __restrict__ WqT_f,
    const short* __restrict__ Wfk_f, const short* __restrict__ WkT_f,
    short* __restrict__ Wcat,
    const float* __restrict__ hs, short* __restrict__ hs_f) {
  __shared__ short lds[2 * 12 * 512];  // BM=64: TOT=12, 24 KB
  if (blockIdx.z == 2) {
    const int bid = blockIdx.y * 16 + blockIdx.x;  // 0..127
    const int stride = 128 * 256;
    for (int i = bid * 256 + threadIdx.x; i < M * E / 4; i += stride) {
      float4 v = ((const float4*)hs)[i];
      ((short4*)hs_f)[i] = make_short4(f2h(v.x), f2h(v.y), f2h(v.z), f2h(v.w));
    }
    return;
  }
  const short* A = blockIdx.z ? Wfk_f : Wfq_f;
  const short* Bm = blockIdx.z ? WkT_f : WqT_f;
  short* C = Wcat + (size_t)blockIdx.z * E * E;  // rows 0..1023 or 1024..2047
  const int bm = blockIdx.x * 64, bn = blockIdx.y * 128;
  f32x4 acc[2][4] = {};
  gemm_core<64>(A, Bm, bm, bn, E, lds, acc);
  const int lane = threadIdx.x & 63, wave = threadIdx.x >> 6;
  const int fr = lane & 15, fq = lane >> 4;
  const int wm = (wave & 1) * 32, wn = (wave >> 1) * 64;
#pragma unroll
  for (int ni = 0; ni < 4; ++ni) {
    const int n = bn + wn + ni * 16 + fr;
#pragma unroll
    for (int mi = 0; mi < 2; ++mi) {
      const int m0 = bm + wm + mi * 16 + fq * 4;
#pragma unroll
      for (int r2 = 0; r2 < 4; ++r2)
        C[(size_t)(m0 + r2) * E + n] = f2h(acc[mi][ni][r2]);
    }
  }
}

// Fused big GEMM: Cbig[M,3072] = hs_f @ [WcQ|WcK|Wv]^T + bcat, epilogue by range:
//   n<1024 (q): store exp(val);  1024..2047 (k): exp + Zk rowsum;  else (v): plain.
// Grid (24 n-blocks, 32 m-blocks) = 768 uniform blocks.
__global__ __launch_bounds__(256, 3) void gemm_big(
    const short* __restrict__ hs_f, const short* __restrict__ Wcat,
    const float* __restrict__ bcat, short* __restrict__ Cb,
    float* __restrict__ Zk) {
  __shared__ short lds[2 * 16 * 512];  // BM=128: TOT=16, 32 KB
  const int bm = blockIdx.y * 128, bn = blockIdx.x * 128;
  f32x4 acc[4][4] = {};
  gemm_core<128>(hs_f, Wcat, bm, bn, E, lds, acc);
  const int lane = threadIdx.x & 63, wave = threadIdx.x >> 6;
  const int fr = lane & 15, fq = lane >> 4;
  const int wm = (wave & 1) * 64, wn = (wave >> 1) * 64;
  const bool doExp = (bn < 2048);
  const bool doZ = (bn >= 1024) && (bn < 2048);
  float bv4[4];
#pragma unroll
  for (int ni = 0; ni < 4; ++ni) bv4[ni] = bcat[bn + wn + ni * 16 + fr];
#pragma unroll
  for (int mi = 0; mi < 4; ++mi)
#pragma unroll
    for (int r2 = 0; r2 < 4; ++r2) {
      const int m = bm + wm + mi * 16 + fq * 4 + r2;
      float vals[4];
#pragma unroll
      for (int ni = 0; ni < 4; ++ni) vals[ni] = acc[mi][ni][r2] + bv4[ni];
      if (doExp) {
#pragma unroll
        for (int ni = 0; ni < 4; ++ni) vals[ni] = __expf(vals[ni]);
      }
      if (doZ) {
        float es = vals[0] + vals[1] + vals[2] + vals[3];
#pragma unroll
        for (int off = 1; off < 16; off <<= 1) es += __shfl_xor(es, off, 16);
        if (fr == 0) atomicAdd(&Zk[m], es);
      }
#pragma unroll
      for (int ni = 0; ni < 4; ++ni)
        Cb[(size_t)m * NBIG + bn + wn + ni * 16 + fr] = f2h(vals[ni]);
    }
}

// Per-chunk KV partials (plain stores; device-atomics regressed in R8).
// Grid (32 bh, CH=8 chunks of 256 t). Reads k=exp/Z (applied inline) and v
// from the fused Cbig buffer (row stride 3072).
__global__ __launch_bounds__(256) void kv_part(const short* __restrict__ Cb,
                                               const float* __restrict__ Zk,
                                               float* __restrict__ KVp,
                                               float* __restrict__ ksump) {
  const int bh = blockIdx.x;
  const int b = bh / H, h = bh % H;
  const int t0 = blockIdx.y * 256;
  const short* kbase = Cb + (size_t)b * S * NBIG + 1024 + h * D;
  const short* vbase = Cb + (size_t)b * S * NBIG + 2048 + h * D;
  __shared__ float ks[16][D];
  __shared__ float vs[16][D];
  __shared__ float invZs[256];
  const int tid = threadIdx.x;
  invZs[tid] = 1.0f / Zk[b * S + t0 + tid];  // batch offset b*S!
  const int a4 = tid & 15, b4 = tid >> 4;
  const int lt = tid >> 4, d4 = (tid & 15) * 4;  // staging: row-in-tile, d offset
  float acc[4][4] = {};
  float ksm[4] = {};
  for (int ts = 0; ts < 256; ts += 16) {
    __syncthreads();
    const size_t roff = (size_t)(t0 + ts + lt) * NBIG + d4;
    short4 k4 = *(const short4*)(kbase + roff);
    short4 v4 = *(const short4*)(vbase + roff);
    const float iz = invZs[ts + lt];
    ks[lt][d4 + 0] = h2f(k4.x) * iz; ks[lt][d4 + 1] = h2f(k4.y) * iz;
    ks[lt][d4 + 2] = h2f(k4.z) * iz; ks[lt][d4 + 3] = h2f(k4.w) * iz;
    vs[lt][d4 + 0] = h2f(v4.x); vs[lt][d4 + 1] = h2f(v4.y);
    vs[lt][d4 + 2] = h2f(v4.z); vs[lt][d4 + 3] = h2f(v4.w);
    __syncthreads();
#pragma unroll
    for (int tt = 0; tt < 16; ++tt) {
      float kk4[4], vv4[4];
#pragma unroll
      for (int i = 0; i < 4; ++i) kk4[i] = ks[tt][a4 * 4 + i];
#pragma unroll
      for (int j = 0; j < 4; ++j) vv4[j] = vs[tt][b4 * 4 + j];
#pragma unroll
      for (int i = 0; i < 4; ++i) {
        ksm[i] += kk4[i];
#pragma unroll
        for (int j = 0; j < 4; ++j) acc[i][j] = fmaf(kk4[i], vv4[j], acc[i][j]);
      }
    }
  }
  float* kvout = KVp + ((size_t)bh * CH + blockIdx.y) * 4096;
#pragma unroll
  for (int i = 0; i < 4; ++i)
    *(float4*)&kvout[(a4 * 4 + i) * 64 + b4 * 4] =
        make_float4(acc[i][0], acc[i][1], acc[i][2], acc[i][3]);
  if (b4 == 0)
    *(float4*)&ksump[((size_t)bh * CH + blockIdx.y) * 64 + a4 * 4] =
        make_float4(ksm[0], ksm[1], ksm[2], ksm[3]);
}

// Output (fuses the partial reduction): grid (32 bh, 32 chunks of 64 rows).
// Reduces CH=8 KV partials into LDS (L2-resident reads), then per-row ratio.
__global__ __launch_bounds__(256) void out_v8(const short* __restrict__ Cb,
                                              const float* __restrict__ KVp,
                                              const float* __restrict__ ksump,
                                              float* __restrict__ out) {
  const int bh = blockIdx.x;
  const int b = bh >> 4, h = bh & 15;
  __shared__ float KVs[64][64];  // float4 reads are 2-way bank-aliased (free)
  __shared__ float kss[64];
  __shared__ float qs[4][4][64];
  const int tid = threadIdx.x, wave = tid >> 6, lane = tid & 63;
  const int r2 = lane >> 4, g = lane & 15;
  for (int i = tid; i < 1024; i += 256) {  // float4 index within 4096
    float4 s = make_float4(0.f, 0.f, 0.f, 0.f);
#pragma unroll
    for (int c = 0; c < CH; ++c) {
      float4 p = ((const float4*)(KVp + ((size_t)bh * CH + c) * 4096))[i];
      s.x += p.x; s.y += p.y; s.z += p.z; s.w += p.w;
    }
    ((float4*)KVs)[i] = s;
  }
  if (tid < 16) {
    float4 s = make_float4(0.f, 0.f, 0.f, 0.f);
#pragma unroll
    for (int c = 0; c < CH; ++c) {
      float4 p = ((const float4*)(ksump + ((size_t)bh * CH + c) * 64))[tid];
      s.x += p.x; s.y += p.y; s.z += p.z; s.w += p.w;
    }
    ((float4*)kss)[tid] = s;
  }
  __syncthreads();
  const float4 ks4 = *(const float4*)&kss[g * 4];
  const int row0 = blockIdx.y * 64 + wave * 16;
#pragma unroll
  for (int it = 0; it < 4; ++it) {
    const int row = row0 + it * 4 + r2;
    // u = stored exp(q logit) fp16 from Cbig (q range, stride 3072)
    short4 us = *(const short4*)(Cb + (size_t)(b * S + row) * NBIG + h * 64 + g * 4);
    float4 u = make_float4(h2f(us.x), h2f(us.y), h2f(us.z), h2f(us.w));
    float dn = u.x * ks4.x + u.y * ks4.y + u.z * ks4.z + u.w * ks4.w;
#pragma unroll
    for (int off = 1; off < 16; off <<= 1) dn += __shfl_xor(dn, off, 16);
    *(float4*)&qs[wave][r2][g * 4] = u;
    __syncthreads();  // publish qs (uniform: all waves run 4 iters)
    float nx = 0.f, ny = 0.f, nz = 0.f, nw = 0.f;
#pragma unroll
    for (int d = 0; d < 64; ++d) {
      const float qd = qs[wave][r2][d];
      const float4 kv = *(const float4*)&KVs[d][g * 4];
      nx = fmaf(qd, kv.x, nx); ny = fmaf(qd, kv.y, ny);
      nz = fmaf(qd, kv.z, nz); nw = fmaf(qd, kv.w, nw);
    }
    const float inv = 1.0f / dn;
    float4 o4 = make_float4(nx * inv, ny * inv, nz * inv, nw * inv);
    const size_t rowoff = ((size_t)b * S + row) * E + h * 64 + g * 4;
    *(float4*)(out + rowoff) = o4;
    __syncthreads();  // qs reused next iteration
  }
}

extern "C" void kernel_launch(void* const* d_in, const int* in_sizes, int n_in,
                              void* d_out, int out_size, void* d_ws, size_t ws_size,
                              hipStream_t stream) {
  const float* hs = (const float*)d_in[0];
  const float* Wq = (const float*)d_in[1];
  const float* bq = (const float*)d_in[2];
  const float* Wk = (const float*)d_in[3];
  const float* bk = (const float*)d_in[4];
  const float* Wv = (const float*)d_in[5];
  const float* bv = (const float*)d_in[6];
  const float* Wfq = (const float*)d_in[7];
  const float* bfq = (const float*)d_in[8];
  const float* Wfk = (const float*)d_in[9];
  const float* bfk = (const float*)d_in[10];
  float* out = (float*)d_out;

  const size_t MEG = 1024 * 1024;
  float* ws = (float*)d_ws;
  short* hs_f = (short*)ws;                            // [0,2M) floats (8 MB)
  short* Wfq_f = (short*)(ws + 2 * MEG);               // 0.5M floats each
  short* Wfk_f = (short*)(ws + 2 * MEG + MEG / 2);
  short* WqT_f = (short*)(ws + 3 * MEG);
  short* WkT_f = (short*)(ws + 3 * MEG + MEG / 2);
  short* Wcat = (short*)(ws + 4 * MEG);                // 3M shorts: [WcQ|WcK|Wv]
  short* Wv_f = Wcat + 2 * MEG;                        // rows 2048..3071
  float* bcat = ws + 6 * MEG;                          // 3072 floats
  float* Zk = bcat + 4096;                             // 4096 floats
  float* KVp = ws + 7 * MEG;                           // 32*CH*4096 = 1M floats
  float* ksump = ws + 8 * MEG;                         // 16K floats
  short* Cbig = (short*)(ws + 9 * MEG);                // M x 3072 fp16 (24 MB)

  // 1) Weight conversions + transposes + bias combines + bv copy + Zk zero.
  prep_w<<<3329, 256, 0, stream>>>(Wfq, Wfq_f, Wfk, Wfk_f, Wv, Wv_f,
                                   Wq, WqT_f, Wk, WkT_f,
                                   bq, bfq, bk, bfk, bv, bcat, Zk);
  // 2) Weight-combine GEMMs (z=0,1) + hs fp16 conversion (z=2), one dispatch.
  wgemm_hs<<<dim3(16, 8, 3), 256, 0, stream>>>(Wfq_f, WqT_f, Wfk_f, WkT_f,
                                               Wcat, hs, hs_f);
  // 3) Fused big GEMM: q|k|v in one N=3072 dispatch (768 uniform blocks).
  gemm_big<<<dim3(24, 32), 256, 0, stream>>>(hs_f, Wcat, bcat, Cbig, Zk);
  // 4) KV partials (256 blocks, plain stores).
  kv_part<<<dim3(B * H, CH), 256, 0, stream>>>(Cbig, Zk, KVp, ksump);
  // 5) Output (1024 blocks; fuses the CH-partial reduction).
  out_v8<<<dim3(B * H, S / 64), 256, 0, stream>>>(Cbig, KVp, ksump, out);
}